// Round 1
// baseline (416.351 us; speedup 1.0000x reference)
//
#include <hip/hip_runtime.h>

// KDE 2D histogram: joint[b,i,j] = sum_n exp(-0.5*((x-bin_i)/bw)^2) * exp(-0.5*((y-bin_j)/bw)^2)
// bw == bin spacing -> kernel support is ~±5.5 bins (beyond that < 3e-7 relative).
// Scatter 12x12 windows into per-(batch,strip) LDS tiles, flush with global f32 atomics,
// then normalize.

#define B_      4
#define N_      50000
#define M_      256
#define SJ      32            // j-columns per strip
#define NSTRIP  (M_ / SJ)     // 8
#define NSUB    16            // particle sub-ranges per strip
#define TSTRIDE 33            // padded tile stride: bank = (i+j)%32, spreads conflicts
#define BLOCK   256
#define WIN     12            // window [c0-5, c0+6]
#define HALF    5
#define CHUNK   1024          // particles scanned per compaction round

__global__ __launch_bounds__(BLOCK) void kde_scatter(
    const float* __restrict__ xs, const float* __restrict__ ys,
    const float* __restrict__ bins, float* __restrict__ joint)
{
    __shared__ float  tile[M_ * TSTRIDE];   // 33792 B
    __shared__ float2 q[CHUNK];             // 8192 B compacted (x,y)
    __shared__ float  sbins[M_];            // 1024 B
    __shared__ int    qcount;

    const int tid   = threadIdx.x;
    const int sub   = blockIdx.x;
    const int strip = blockIdx.y;
    const int b     = blockIdx.z;

    sbins[tid] = bins[tid];                       // BLOCK == M_
    for (int c = tid; c < M_ * TSTRIDE; c += BLOCK) tile[c] = 0.0f;
    if (tid == 0) qcount = 0;
    __syncthreads();

    const float bin0   = sbins[0];
    const float inv_bw = 1.0f / (sbins[1] - sbins[0]);
    const int   jlo    = strip * SJ;
    const int   jhi    = jlo + SJ;
    const float* xb = xs + b * N_;
    const float* yb = ys + b * N_;

    const int per     = (N_ + NSUB - 1) / NSUB;
    const int n_begin = sub * per;
    const int n_end   = min(N_, n_begin + per);

    for (int base = n_begin; base < n_end; base += CHUNK) {
        const int cnt = min(CHUNK, n_end - base);

        // ---- scan + compact: keep particles whose j-window touches this strip ----
        for (int t = tid; t < cnt; t += BLOCK) {
            const float y  = yb[base + t];
            const float v  = (y - bin0) * inv_bw;
            const int   j0 = (int)rintf(v);
            const int   js = max(max(j0 - HALF, jlo), 0);
            const int   je = min(min(j0 + HALF + 1, jhi), M_) - 1;
            if (js <= je) {
                const int slot = atomicAdd(&qcount, 1);
                q[slot] = make_float2(xb[base + t], y);
            }
        }
        __syncthreads();
        const int m = qcount;

        // ---- process queue with dense exec masks ----
        for (int t = tid; t < m; t += BLOCK) {
            const float2 p  = q[t];
            const float  x  = p.x, yy = p.y;
            const float  u  = (x  - bin0) * inv_bw;
            const float  v  = (yy - bin0) * inv_bw;
            const int    i0 = (int)rintf(u);
            const int    j0 = (int)rintf(v);

            float kx[WIN], ky[WIN];
            #pragma unroll
            for (int a = 0; a < WIN; ++a) {
                const int   ii  = i0 - HALF + a;
                const int   iic = min(max(ii, 0), M_ - 1);
                const float d   = (x - sbins[iic]) * inv_bw;
                kx[a] = (ii == iic) ? __expf(-0.5f * d * d) : 0.0f;

                const int   jj  = j0 - HALF + a;
                const int   jjc = min(max(jj, 0), M_ - 1);
                const float e   = (yy - sbins[jjc]) * inv_bw;
                ky[a] = (jj == jjc && jj >= jlo && jj < jhi)
                            ? __expf(-0.5f * e * e) : 0.0f;
            }

            const int colbase = j0 - HALF - jlo;  // tile column of window start
            #pragma unroll
            for (int a = 0; a < WIN; ++a) {
                const float kxv = kx[a];
                if (kxv != 0.0f) {
                    const int row = (i0 - HALF + a) * TSTRIDE + colbase;
                    #pragma unroll
                    for (int c = 0; c < WIN; ++c) {
                        const float w = kxv * ky[c];
                        if (w != 0.0f) atomicAdd(&tile[row + c], w);
                    }
                }
            }
        }
        __syncthreads();
        if (tid == 0) qcount = 0;
        __syncthreads();
    }

    // ---- flush tile -> global (zero-skip) ----
    float* jb = joint + (size_t)b * M_ * M_ + jlo;
    for (int c = tid; c < M_ * SJ; c += BLOCK) {
        const int   i  = c >> 5;        // SJ == 32
        const int   jj = c & (SJ - 1);
        const float v  = tile[i * TSTRIDE + jj];
        if (v != 0.0f) unsafeAtomicAdd(&jb[(size_t)i * M_ + jj], v);
    }
}

__global__ __launch_bounds__(1024) void kde_norm(
    const float* __restrict__ joint, float* __restrict__ inv)
{
    __shared__ double red[1024];
    const int b = blockIdx.x;
    const float* p = joint + (size_t)b * M_ * M_;
    double s = 0.0;
    for (int i = threadIdx.x; i < M_ * M_; i += 1024) s += (double)p[i];
    red[threadIdx.x] = s;
    __syncthreads();
    for (int off = 512; off > 0; off >>= 1) {
        if (threadIdx.x < off) red[threadIdx.x] += red[threadIdx.x + off];
        __syncthreads();
    }
    if (threadIdx.x == 0) inv[b] = (float)(1.0 / (red[0] + 1e-10));
}

__global__ __launch_bounds__(256) void kde_scale(
    float* __restrict__ out, const float* __restrict__ inv)
{
    const int idx = blockIdx.x * 256 + threadIdx.x;   // B_*M_*M_/4 float4s
    const float s = inv[idx >> 14];                   // 16384 float4 per batch
    float4* o = reinterpret_cast<float4*>(out);
    float4 v = o[idx];
    v.x *= s; v.y *= s; v.z *= s; v.w *= s;
    o[idx] = v;
}

extern "C" void kernel_launch(void* const* d_in, const int* in_sizes, int n_in,
                              void* d_out, int out_size, void* d_ws, size_t ws_size,
                              hipStream_t stream)
{
    const float* xs   = (const float*)d_in[0];
    const float* ys   = (const float*)d_in[1];
    const float* bins = (const float*)d_in[2];
    float* out = (float*)d_out;
    float* inv = (float*)d_ws;   // 4 floats

    hipMemsetAsync(d_out, 0, (size_t)B_ * M_ * M_ * sizeof(float), stream);

    dim3 grid(NSUB, NSTRIP, B_);
    kde_scatter<<<grid, BLOCK, 0, stream>>>(xs, ys, bins, out);
    kde_norm<<<B_, 1024, 0, stream>>>(out, inv);
    kde_scale<<<(B_ * M_ * M_ / 4) / 256, 256, 0, stream>>>(out, inv);
}

// Round 2
// 296.997 us; speedup vs baseline: 1.4019x; 1.4019x over previous
//
#include <hip/hip_runtime.h>

// KDE joint histogram, gather formulation.
// joint[b,i,j] = sum_n exp(-0.5*((x_n-bin_i)/bw)^2) * exp(-0.5*((y_n-bin_j)/bw)^2)
// Gaussian support ~ +-5.5 bins (tail < 2.7e-7 relative). Each block owns a
// 16x16 output tile, each thread ONE cell in a register. Scan+compact the
// batch's particles into an LDS queue (window-intersects-tile test, ~1% pass),
// then all threads sweep the queue with pure VALU work (2 exp + 1 fma per
// particle per cell). No LDS/global atomics on the hot path.

#define B_     4
#define N_     50000
#define M_     256
#define TILE   16
#define BLOCK  256
#define SCHUNK 2048     // particles scanned per compaction round
#define HALFW  5.5f     // half window width (bins) for tile-intersect test

// exp(-0.5*d^2) computed as exp2(-(d*C)^2), C = sqrt(0.5*log2(e))
#define CSCALE 0.84932180f
#if __has_builtin(__builtin_amdgcn_exp2f)
  #define EXPN(t2) __builtin_amdgcn_exp2f(-(t2))          // 2^-t2
#else
  #define EXPN(t2) __expf(-(t2) * 0.69314718f)
#endif

__global__ __launch_bounds__(BLOCK) void kde_gather(
    const float* __restrict__ xs, const float* __restrict__ ys,
    const float* __restrict__ bins, float* __restrict__ out,
    float* __restrict__ norm)
{
    __shared__ float2 q[SCHUNK];   // 16 KB: compacted (x*s, y*s)
    __shared__ float  red[BLOCK / 64];
    __shared__ int    qn;

    const int tid = threadIdx.x;
    const int ti  = blockIdx.x;       // row tile (x axis / i)
    const int tj  = blockIdx.y;       // col tile (y axis / j)
    const int b   = blockIdx.z;

    const float bin0  = bins[0];
    const float invbw = 1.0f / (bins[1] - bin0);
    const float s     = invbw * CSCALE;

    const int ilo = ti * TILE, jlo = tj * TILE;
    const int ci  = ilo + (tid >> 4);     // this thread's output row
    const int cj  = jlo + (tid & 15);     // this thread's output col
    const float bxs = bins[ci] * s;       // cell-bin constants in registers
    const float bys = bins[cj] * s;

    // tile-intersect bounds in fractional-bin coordinates
    const float ulo = (float)ilo - HALFW, uhi = (float)(ilo + TILE - 1) + HALFW;
    const float vlo = (float)jlo - HALFW, vhi = (float)(jlo + TILE - 1) + HALFW;

    const float* xb = xs + b * N_;
    const float* yb = ys + b * N_;

    float acc = 0.0f;
    if (tid == 0) qn = 0;
    __syncthreads();

    for (int base = 0; base < N_; base += SCHUNK) {
        const int cnt = min(SCHUNK, N_ - base);

        // ---- scan + compact ----
        for (int t = tid; t < cnt; t += BLOCK) {
            const float x = xb[base + t];
            const float y = yb[base + t];
            const float u = (x - bin0) * invbw;
            const float v = (y - bin0) * invbw;
            if (u >= ulo && u <= uhi && v >= vlo && v <= vhi) {
                const int slot = atomicAdd(&qn, 1);   // cap == SCHUNK, can't overflow
                q[slot] = make_float2(x * s, y * s);
            }
        }
        __syncthreads();
        const int m = qn;

        // ---- dense sweep: every thread accumulates its own cell ----
        int t = 0;
        for (; t + 4 <= m; t += 4) {
            const float2 p0 = q[t], p1 = q[t+1], p2 = q[t+2], p3 = q[t+3];
            float tx, ty, ex, ey;
            tx = p0.x - bxs; ty = p0.y - bys;
            ex = EXPN(tx*tx); ey = EXPN(ty*ty); acc = fmaf(ex, ey, acc);
            tx = p1.x - bxs; ty = p1.y - bys;
            ex = EXPN(tx*tx); ey = EXPN(ty*ty); acc = fmaf(ex, ey, acc);
            tx = p2.x - bxs; ty = p2.y - bys;
            ex = EXPN(tx*tx); ey = EXPN(ty*ty); acc = fmaf(ex, ey, acc);
            tx = p3.x - bxs; ty = p3.y - bys;
            ex = EXPN(tx*tx); ey = EXPN(ty*ty); acc = fmaf(ex, ey, acc);
        }
        for (; t < m; ++t) {
            const float2 p = q[t];
            const float tx = p.x - bxs, ty = p.y - bys;
            const float ex = EXPN(tx*tx), ey = EXPN(ty*ty);
            acc = fmaf(ex, ey, acc);
        }
        __syncthreads();
        if (tid == 0) qn = 0;
        __syncthreads();
    }

    // ---- direct store (this thread exclusively owns its cell) ----
    out[((size_t)b * M_ + ci) * M_ + cj] = acc;

    // ---- fused norm partial: block-reduce acc, one float atomic per block ----
    float r = acc;
    #pragma unroll
    for (int off = 32; off > 0; off >>= 1) r += __shfl_xor(r, off);
    if ((tid & 63) == 0) red[tid >> 6] = r;
    __syncthreads();
    if (tid == 0) {
        float tot = red[0] + red[1] + red[2] + red[3];
        unsafeAtomicAdd(&norm[b], tot);
    }
}

__global__ __launch_bounds__(BLOCK) void kde_scale(
    float* __restrict__ out, const float* __restrict__ norm)
{
    const int idx = blockIdx.x * BLOCK + threadIdx.x;   // over float4s
    const float sc = 1.0f / (norm[idx >> 14] + 1e-10f); // 16384 float4 per batch
    float4* o = reinterpret_cast<float4*>(out);
    float4 v = o[idx];
    v.x *= sc; v.y *= sc; v.z *= sc; v.w *= sc;
    o[idx] = v;
}

extern "C" void kernel_launch(void* const* d_in, const int* in_sizes, int n_in,
                              void* d_out, int out_size, void* d_ws, size_t ws_size,
                              hipStream_t stream)
{
    const float* xs   = (const float*)d_in[0];
    const float* ys   = (const float*)d_in[1];
    const float* bins = (const float*)d_in[2];
    float* out  = (float*)d_out;
    float* norm = (float*)d_ws;   // 4 floats

    hipMemsetAsync(d_ws, 0, 4 * sizeof(float), stream);
    kde_gather<<<dim3(M_ / TILE, M_ / TILE, B_), BLOCK, 0, stream>>>(xs, ys, bins, out, norm);
    kde_scale<<<(B_ * M_ * M_ / 4) / BLOCK, BLOCK, 0, stream>>>(out, norm);
}

// Round 3
// 133.618 us; speedup vs baseline: 3.1160x; 2.2227x over previous
//
#include <hip/hip_runtime.h>

// KDE joint histogram as a dense split-K bf16 MFMA GEMM.
// joint[b,i,j] = sum_k kx[b,k,i]*ky[b,k,j],  kx = exp(-0.5*((x-bin_i)/bw)^2).
// kx/ky tiles are computed on the fly (exp2) into LDS as bf16, consumed by
// mfma_f32_16x16x32_bf16. Split-K partials -> d_ws (32 MB) -> reduce(+norm)
// -> scale. Fallback to global fp32 atomics if ws is too small.
// Every block does identical work: perfectly balanced, no divergence.

#define B_     4
#define N_     50000
#define M_     256
#define BM     128
#define BN     128
#define BK     64
#define NCH    32               // split-K chunks: grid 4*32*4 = 512 = 2 blocks/CU
#define KSTEPS 25               // 25*64 = 1600 per chunk; 32*1600 = 51200 >= N
#define KCH    (KSTEPS * BK)
#define LDK    (BK + 8)         // 72 shorts = 144 B row stride (16B-aligned, depads banks)
#define BLOCK  256
#define CSCALE 0.84932180f      // sqrt(0.5*log2(e)):  exp(-0.5 d^2) = 2^(-(d*CSCALE)^2)

#if __has_builtin(__builtin_amdgcn_exp2f)
  #define EXPN(t2) __builtin_amdgcn_exp2f(-(t2))
#else
  #define EXPN(t2) __expf(-(t2) * 0.69314718f)
#endif

typedef __attribute__((ext_vector_type(8))) short bf16x8;
typedef __attribute__((ext_vector_type(4))) float f32x4;

__device__ __forceinline__ short f2bf(float f) {   // round-half-up to bf16
    union { float f; unsigned u; } v; v.f = f;
    return (short)((v.u + 0x8000u) >> 16);
}

__global__ __launch_bounds__(BLOCK) void kde_gemm(
    const float* __restrict__ xs, const float* __restrict__ ys,
    const float* __restrict__ bins, float* __restrict__ partial,
    float* __restrict__ out, float* __restrict__ norm, int use_ws)
{
    __shared__ short As[BM][LDK];     // 18432 B  kx tile [i-bin][k]
    __shared__ short Bs[BN][LDK];     // 18432 B  ky tile [j-bin][k]
    __shared__ float px[KCH];         // 6400 B   x*s for this K-chunk
    __shared__ float py[KCH];         // 6400 B
    __shared__ float red[4];

    const int tid   = threadIdx.x;
    const int tile  = blockIdx.x;            // 0..3 -> 2x2 tiles of 128
    const int chunk = blockIdx.y;            // 0..NCH-1
    const int b     = blockIdx.z;

    const int ilo = (tile & 1) * BM;
    const int jlo = (tile >> 1) * BN;
    const float s = CSCALE / (bins[1] - bins[0]);

    // ---- stage this chunk's particles (scaled) into LDS ----
    const float* xb = xs + b * N_;
    const float* yb = ys + b * N_;
    const int k0 = chunk * KCH;
    for (int t = tid; t < KCH; t += BLOCK) {
        const int k = k0 + t;
        const bool ok = (k < N_);
        px[t] = ok ? xb[k] * s : 3.0e30f;    // pad: (3e30)^2 -> inf -> exp2(-inf)=0
        py[t] = ok ? yb[k] * s : 3.0e30f;
    }

    // staging role: thread covers bin=tid>>1, k-half kh
    const int  sbin = tid >> 1;
    const int  kh   = (tid & 1) * 32;
    const float bxs = bins[ilo + sbin] * s;
    const float bys = bins[jlo + sbin] * s;

    // MFMA role: 4 waves in 2x2, each owns 64x64 of the 128x128 tile
    const int w    = tid >> 6;
    const int wi   = (w >> 1) * 64;
    const int wj   = (w & 1) * 64;
    const int lane = tid & 63;
    const int lm   = lane & 15;
    const int quad = lane >> 4;

    f32x4 zero = {0.f, 0.f, 0.f, 0.f};
    f32x4 acc[4][4];
    #pragma unroll
    for (int mt = 0; mt < 4; ++mt)
        #pragma unroll
        for (int nt = 0; nt < 4; ++nt) acc[mt][nt] = zero;

    for (int ks = 0; ks < KSTEPS; ++ks) {
        const int kb = ks * BK;
        __syncthreads();                      // also covers px/py staging on ks==0
        // ---- compute 32 kx + 32 ky bf16 elements into LDS ----
        #pragma unroll
        for (int g = 0; g < 4; ++g) {
            const int k8 = kb + kh + g * 8;
            const float4 xa = *(const float4*)&px[k8];
            const float4 xc = *(const float4*)&px[k8 + 4];
            const float4 ya = *(const float4*)&py[k8];
            const float4 yc = *(const float4*)&py[k8 + 4];
            const float fx[8] = {xa.x, xa.y, xa.z, xa.w, xc.x, xc.y, xc.z, xc.w};
            const float fy[8] = {ya.x, ya.y, ya.z, ya.w, yc.x, yc.y, yc.z, yc.w};
            bf16x8 av, bv;
            #pragma unroll
            for (int e = 0; e < 8; ++e) {
                const float tx = fx[e] - bxs;
                const float ty = fy[e] - bys;
                av[e] = f2bf(EXPN(tx * tx));
                bv[e] = f2bf(EXPN(ty * ty));
            }
            *(bf16x8*)&As[sbin][kh + g * 8] = av;
            *(bf16x8*)&Bs[sbin][kh + g * 8] = bv;
        }
        __syncthreads();
        // ---- consume: 2 K-steps of 32, 16 MFMAs each ----
        #pragma unroll
        for (int kk = 0; kk < BK; kk += 32) {
            bf16x8 af[4], bf[4];
            #pragma unroll
            for (int t4 = 0; t4 < 4; ++t4)
                af[t4] = *(const bf16x8*)&As[wi + t4 * 16 + lm][kk + quad * 8];
            #pragma unroll
            for (int t4 = 0; t4 < 4; ++t4)
                bf[t4] = *(const bf16x8*)&Bs[wj + t4 * 16 + lm][kk + quad * 8];
            #pragma unroll
            for (int mt = 0; mt < 4; ++mt)
                #pragma unroll
                for (int nt = 0; nt < 4; ++nt)
                    acc[mt][nt] = __builtin_amdgcn_mfma_f32_16x16x32_bf16(
                        af[mt], bf[nt], acc[mt][nt], 0, 0, 0);
        }
    }

    // ---- epilogue: C/D layout col=lane&15, row=quad*4+reg ----
    float tsum = 0.f;
    if (use_ws) {
        float* pb = partial + (((size_t)chunk * B_ + b) << 16);
        #pragma unroll
        for (int mt = 0; mt < 4; ++mt) {
            const int row0 = ilo + wi + mt * 16 + quad * 4;
            #pragma unroll
            for (int nt = 0; nt < 4; ++nt) {
                const int col = jlo + wj + nt * 16 + lm;
                const f32x4 a = acc[mt][nt];
                #pragma unroll
                for (int e = 0; e < 4; ++e) {
                    pb[(size_t)(row0 + e) * M_ + col] = a[e];
                }
            }
        }
    } else {
        float* ob = out + ((size_t)b << 16);
        #pragma unroll
        for (int mt = 0; mt < 4; ++mt) {
            const int row0 = ilo + wi + mt * 16 + quad * 4;
            #pragma unroll
            for (int nt = 0; nt < 4; ++nt) {
                const int col = jlo + wj + nt * 16 + lm;
                const f32x4 a = acc[mt][nt];
                #pragma unroll
                for (int e = 0; e < 4; ++e) {
                    const float v = a[e];
                    unsafeAtomicAdd(&ob[(size_t)(row0 + e) * M_ + col], v);
                    tsum += v;
                }
            }
        }
        #pragma unroll
        for (int off = 32; off; off >>= 1) tsum += __shfl_xor(tsum, off);
        if (lane == 0) red[w] = tsum;
        __syncthreads();
        if (tid == 0) unsafeAtomicAdd(&norm[b], red[0] + red[1] + red[2] + red[3]);
    }
}

__global__ __launch_bounds__(BLOCK) void kde_reduce(
    const float* __restrict__ partial, float* __restrict__ out,
    float* __restrict__ norm)
{
    __shared__ float red[4];
    const int b   = blockIdx.y;
    const int idx = blockIdx.x * BLOCK + threadIdx.x;     // float4 index in batch
    const float4* p = (const float4*)partial;
    float4 a = {0.f, 0.f, 0.f, 0.f};
    #pragma unroll 4
    for (int c = 0; c < NCH; ++c) {
        const float4 v = p[(((size_t)c * B_ + b) << 14) + idx];
        a.x += v.x; a.y += v.y; a.z += v.z; a.w += v.w;
    }
    ((float4*)out)[((size_t)b << 14) + idx] = a;
    float t = a.x + a.y + a.z + a.w;
    #pragma unroll
    for (int off = 32; off; off >>= 1) t += __shfl_xor(t, off);
    if ((threadIdx.x & 63) == 0) red[threadIdx.x >> 6] = t;
    __syncthreads();
    if (threadIdx.x == 0) unsafeAtomicAdd(&norm[b], red[0] + red[1] + red[2] + red[3]);
}

__global__ __launch_bounds__(BLOCK) void kde_scale(
    float* __restrict__ out, const float* __restrict__ norm)
{
    const int idx = blockIdx.x * BLOCK + threadIdx.x;     // over float4s
    const float sc = 1.0f / (norm[idx >> 14] + 1e-10f);   // 16384 float4 per batch
    float4* o = reinterpret_cast<float4*>(out);
    float4 v = o[idx];
    v.x *= sc; v.y *= sc; v.z *= sc; v.w *= sc;
    o[idx] = v;
}

extern "C" void kernel_launch(void* const* d_in, const int* in_sizes, int n_in,
                              void* d_out, int out_size, void* d_ws, size_t ws_size,
                              hipStream_t stream)
{
    const float* xs   = (const float*)d_in[0];
    const float* ys   = (const float*)d_in[1];
    const float* bins = (const float*)d_in[2];
    float* out = (float*)d_out;

    const size_t PSZ = (size_t)NCH * B_ * M_ * M_ * sizeof(float);  // 32 MB
    const int use_ws = (ws_size >= PSZ + 64) ? 1 : 0;
    float* partial = (float*)d_ws;
    float* norm    = use_ws ? (float*)((char*)d_ws + PSZ) : (float*)d_ws;

    hipMemsetAsync(norm, 0, 4 * sizeof(float), stream);
    if (!use_ws)
        hipMemsetAsync(d_out, 0, (size_t)B_ * M_ * M_ * sizeof(float), stream);

    kde_gemm<<<dim3(4, NCH, B_), BLOCK, 0, stream>>>(xs, ys, bins, partial, out, norm, use_ws);
    if (use_ws)
        kde_reduce<<<dim3(M_ * M_ / (4 * BLOCK), B_), BLOCK, 0, stream>>>(partial, out, norm);
    kde_scale<<<(B_ * M_ * M_ / 4) / BLOCK, BLOCK, 0, stream>>>(out, norm);
}